// Round 14
// baseline (103.795 us; speedup 1.0000x reference)
//
#include <hip/hip_runtime.h>

// Direct-to-fragment separable projector v5 (occupancy-first).
// R13 lesson: exp-work cut delivered 0 (regression == added partial traffic)
// => k_proj is stall-bound at 2 waves/SIMD, not issue-bound. R14: wave covers
// 64r x 32c (acc = 2 x floatx16 = 32 VGPR), no manual prefetch arrays, block
// covers a 64-row half (QSPLIT=2, image-split does NOT grow partial traffic),
// launch_bounds(256,4) -> 1024 blocks, 16 waves/CU, 4/SIMD (2x R12).
// NS=32/PER=640 keeps partials at 16.8 MB f16. Fixed floor: ws-poison ~40us.

#define S 128
#define NS 32            // K-splits: 31 x 640 + 1 x 160 atoms, both /16
#define PER 640
#define QS 2             // row-half splits of the image per (b,ks)
#define BLOCK 256        // 4 waves; wave w covers cols [w*32, w*32+32)

typedef _Float16 f16;
typedef _Float16 f16x2 __attribute__((ext_vector_type(2)));
typedef _Float16 f16x8 __attribute__((ext_vector_type(8)));
typedef float floatx16 __attribute__((ext_vector_type(16)));

#if __has_builtin(__builtin_amdgcn_exp2f)
#define FAST_EXP2(x) __builtin_amdgcn_exp2f(x)
#else
#define FAST_EXP2(x) exp2f(x)
#endif
#if __has_builtin(__builtin_amdgcn_rcpf)
#define FAST_RCP(x) __builtin_amdgcn_rcpf(x)
#else
#define FAST_RCP(x) (1.0f / (x))
#endif

static __device__ __forceinline__ f16x2 PKRTZ(float a, float b) {
#if __has_builtin(__builtin_amdgcn_cvt_pkrtz)
    return __builtin_bit_cast(f16x2, __builtin_amdgcn_cvt_pkrtz(a, b));
#else
    return (f16x2){(f16)a, (f16)b};
#endif
}

union frag_u { f16x8 v; f16x2 h[4]; };

__global__ __launch_bounds__(BLOCK, 4) void k_proj(
    const float* __restrict__ mol,   // (B, A, 3)
    const float* __restrict__ stds,  // (A)
    const float* __restrict__ dens,  // (A)
    f16* __restrict__ part,          // (B*NS, 128*128) f16 partials, frag order
    int B, int A)
{
    __shared__ float4 sP[PER];       // (x, y, k=-0.5*log2e/var, c2=log2(coef))

    const int ks   = blockIdx.x;
    const int q    = blockIdx.y;     // row half: rows [q*64, q*64+64)
    const int b    = blockIdx.z;
    const int tid  = threadIdx.x;
    const int lane = tid & 63;
    const int wav  = tid >> 6;       // col quarter: cols [wav*32, wav*32+32)
    const int l31  = lane & 31;
    const int hi   = lane >> 5;

    const int a0  = ks * PER;
    const int a1  = min(a0 + PER, A);
    const int cnt = a1 - a0;          // 640 or 160, both /16 (no dead atoms)

    for (int i = tid; i < cnt; i += BLOCK) {
        const int a = a0 + i;
        const size_t idx = (size_t)b * A + a;
        float x  = mol[idx * 3 + 0];
        float y  = mol[idx * 3 + 1];
        float v  = stds[a] * stds[a];
        float rv = FAST_RCP(v);
        sP[i] = make_float4(x, y, -0.72134752044448f * rv,
                            __log2f(dens[a] * 0.15915494309189535f * rv));
    }
    __syncthreads();   // the only barrier

    const float py0 = (float)(q * 64 + l31) - 63.5f;    // A row, tile 0
    const float px0 = (float)(wav * 32 + l31) - 63.5f;  // B col (single tile)

    floatx16 acc0 = {0.f}, acc1 = {0.f};   // rows +0 / +32 of this wave's tile

    const int nk = cnt >> 4;
    const float4* sp = sP + hi * 8;

    for (int s = 0; s < nk; ++s) {
        const float4* pp = sp + (size_t)s * 16;
        frag_u A0, A1, B0;
#pragma unroll
        for (int jp = 0; jp < 4; ++jp) {
            float ea0[2], ea1[2], eb0[2];
#pragma unroll
            for (int u = 0; u < 2; ++u) {
                float4 p = pp[2 * jp + u];
                float dy = py0 - p.y;
                float t  = p.z * dy;
                float g0 = fmaf(t, dy, p.w);
                float g1 = fmaf(1024.0f, p.z, fmaf(64.0f, t, g0));  // row +32
                ea0[u] = FAST_EXP2(g0);
                ea1[u] = FAST_EXP2(g1);
                float dx = px0 - p.x;
                eb0[u] = FAST_EXP2((p.z * dx) * dx);
            }
            A0.h[jp] = PKRTZ(ea0[0], ea0[1]);
            A1.h[jp] = PKRTZ(ea1[0], ea1[1]);
            B0.h[jp] = PKRTZ(eb0[0], eb0[1]);
        }
        acc0 = __builtin_amdgcn_mfma_f32_32x32x16_f16(A0.v, B0.v, acc0, 0, 0, 0);
        acc1 = __builtin_amdgcn_mfma_f32_32x32x16_f16(A1.v, B0.v, acc1, 0, 0, 0);
    }

    // f16 partial store, frag order: idx = (r*4 + c)*1024 + lane*16 + reg.
    // This wave's tiles: r = q*2 + rr (rr=0,1), c = wav  (disjoint across blocks).
    f16* base = part + ((size_t)(b * NS + ks)) * (S * S) + lane * 16;
    floatx16 accs[2] = {acc0, acc1};
#pragma unroll
    for (int rr = 0; rr < 2; ++rr) {
        f16* pq = base + (size_t)((q * 2 + rr) * 4 + wav) * 1024;
        frag_u lo, hiv;
#pragma unroll
        for (int jp = 0; jp < 4; ++jp) {
            lo.h[jp]  = PKRTZ(accs[rr][2 * jp],     accs[rr][2 * jp + 1]);
            hiv.h[jp] = PKRTZ(accs[rr][2 * jp + 8], accs[rr][2 * jp + 9]);
        }
        *(f16x8*)(pq + 0) = lo.v;
        *(f16x8*)(pq + 8) = hiv.v;
    }
}

// sum NS f16 partials per batch (f16x8 coalesced reads), un-permute, write f32.
__global__ __launch_bounds__(256) void k_reduce(const f16* __restrict__ part,
                                                float* __restrict__ out) {
    const int b  = blockIdx.z;
    const int f8 = (blockIdx.x * 256 + threadIdx.x) * 8;   // frag-order base idx

    const f16* src = part + (size_t)b * NS * (S * S) + f8;
    float s0[8] = {0.f}, s1[8] = {0.f};
    for (int s = 0; s < NS; s += 2) {                      // NS even
        f16x8 v0 = *(const f16x8*)&src[(size_t)s * (S * S)];
        f16x8 v1 = *(const f16x8*)&src[(size_t)(s + 1) * (S * S)];
#pragma unroll
        for (int i = 0; i < 8; ++i) { s0[i] += (float)v0[i]; s1[i] += (float)v1[i]; }
    }

    // decode f8 = tile*1024 + lane*16 + reg0; tile = r*4 + c (32x32 tiles)
    const int reg0 = f8 & 15;
    const int lane = (f8 >> 4) & 63;
    const int tile = f8 >> 10;
    const int r    = tile >> 2;
    const int cc   = tile & 3;
    // mfma_32x32 C/D: col = lane&31, row = (reg&3) + 8*(reg>>2) + 4*(lane>>5)
    const int rowb = r * 32 + 4 * (lane >> 5);
    const int col  = cc * 32 + (lane & 31);
#pragma unroll
    for (int i = 0; i < 8; ++i) {
        const int reg = reg0 + i;
        const int row = rowb + (reg & 3) + 8 * (reg >> 2);
        out[((size_t)b * S + row) * S + col] = s0[i] + s1[i];
    }
}

extern "C" void kernel_launch(void* const* d_in, const int* in_sizes, int n_in,
                              void* d_out, int out_size, void* d_ws, size_t ws_size,
                              hipStream_t stream) {
    const float* mol  = (const float*)d_in[0];
    const float* stds = (const float*)d_in[1];
    const float* dens = (const float*)d_in[2];
    float* out = (float*)d_out;

    const int A = in_sizes[1];             // 20000
    const int B = in_sizes[0] / (A * 3);   // 16

    f16* part = (f16*)d_ws;                // B*NS*16384*2 = 16.8 MB

    k_proj<<<dim3(NS, QS, B), dim3(BLOCK), 0, stream>>>(mol, stds, dens, part, B, A);
    k_reduce<<<dim3((S * S) / (256 * 8), 1, B), dim3(256), 0, stream>>>(part, out);
}

// Round 15
// 93.364 us; speedup vs baseline: 1.1117x; 1.1117x over previous
//
#include <hip/hip_runtime.h>

// Direct-to-fragment separable projector v6 (atom-split waves).
// R14 lesson: 4 waves/SIMD lifted VALUBusy 45->68% but 64x32 waves cost 3x exp
// redundancy (251M lane-exps) -> net wash vs R12 (2x, 167M, 2 waves/SIMD).
// Constraint: waves x px/wave = B*NS*16384 -- more waves via pixel-splitting
// always raises redundancy. R15: split ATOMS instead. Block (b,ks) = 8 waves =
// 4 quadrants (64x64, acc 64 VGPR, 2x redundancy) x 2 atom-halves (320 each);
// cross-half f32 reduce through LDS at the end (one extra barrier). 4 waves/SIMD
// at R12's work level; partials stay NS=32 = 16.8 MB f16.

#define S 128
#define NS 32            // K-splits: 31 x 640 + 1 x 160 atoms
#define PER 640
#define BLOCK 512        // 8 waves: wav&3 = quadrant, wav>>2 = atom half

typedef _Float16 f16;
typedef _Float16 f16x2 __attribute__((ext_vector_type(2)));
typedef _Float16 f16x8 __attribute__((ext_vector_type(8)));
typedef float floatx16 __attribute__((ext_vector_type(16)));

#if __has_builtin(__builtin_amdgcn_exp2f)
#define FAST_EXP2(x) __builtin_amdgcn_exp2f(x)
#else
#define FAST_EXP2(x) exp2f(x)
#endif
#if __has_builtin(__builtin_amdgcn_rcpf)
#define FAST_RCP(x) __builtin_amdgcn_rcpf(x)
#else
#define FAST_RCP(x) (1.0f / (x))
#endif

static __device__ __forceinline__ f16x2 PKRTZ(float a, float b) {
#if __has_builtin(__builtin_amdgcn_cvt_pkrtz)
    return __builtin_bit_cast(f16x2, __builtin_amdgcn_cvt_pkrtz(a, b));
#else
    return (f16x2){(f16)a, (f16)b};
#endif
}

union frag_u { f16x8 v; f16x2 h[4]; };

__global__ __launch_bounds__(BLOCK, 4) void k_proj(
    const float* __restrict__ mol,   // (B, A, 3)
    const float* __restrict__ stds,  // (A)
    const float* __restrict__ dens,  // (A)
    f16* __restrict__ part,          // (B*NS, 128*128) f16 partials, frag order
    int B, int A)
{
    __shared__ float4 sP[PER];       // 10 KB: (x, y, k, c2)
    __shared__ float red[4 * 4096];  // 64 KB: per-quadrant cross-half reduce

    const int ks   = blockIdx.x;
    const int b    = blockIdx.y;
    const int tid  = threadIdx.x;
    const int lane = tid & 63;
    const int wav  = tid >> 6;
    const int quad = wav & 3;        // image quadrant (64x64)
    const int half = wav >> 2;       // atom half
    const int l31  = lane & 31;
    const int hi   = lane >> 5;

    const int a0  = ks * PER;
    const int a1  = min(a0 + PER, A);
    const int cnt = a1 - a0;          // 640 or 160

    for (int i = tid; i < cnt; i += BLOCK) {
        const int a = a0 + i;
        const size_t idx = (size_t)b * A + a;
        float x  = mol[idx * 3 + 0];
        float y  = mol[idx * 3 + 1];
        float v  = stds[a] * stds[a];
        float rv = FAST_RCP(v);
        sP[i] = make_float4(x, y, -0.72134752044448f * rv,
                            __log2f(dens[a] * 0.15915494309189535f * rv));
    }
    __syncthreads();

    const int hcnt = cnt >> 1;        // 320 or 80, both /16
    const int nk   = hcnt >> 4;       // 20 or 5

    const float py0 = (float)((quad >> 1) * 64 + l31) - 63.5f;  // A row, tile 0
    const float px0 = (float)((quad & 1) * 64 + l31) - 63.5f;   // B col, tile 0

    floatx16 acc[2][2];
#pragma unroll
    for (int rr = 0; rr < 2; ++rr)
#pragma unroll
        for (int cb = 0; cb < 2; ++cb) acc[rr][cb] = (floatx16){0.f};

    const float4* sp = sP + half * hcnt + hi * 8;

    for (int s = 0; s < nk; ++s) {
        const float4* pp = sp + (size_t)s * 16;
        frag_u A0, A1, B0, B1;
#pragma unroll
        for (int jp = 0; jp < 4; ++jp) {
            float ea0[2], ea1[2], eb0[2], eb1[2];
#pragma unroll
            for (int u = 0; u < 2; ++u) {
                float4 p = pp[2 * jp + u];
                float dy = py0 - p.y;
                float t  = p.z * dy;
                float g0 = fmaf(t, dy, p.w);
                float g1 = fmaf(1024.0f, p.z, fmaf(64.0f, t, g0));   // row +32
                ea0[u] = FAST_EXP2(g0);
                ea1[u] = FAST_EXP2(g1);
                float dx = px0 - p.x;
                float sx = p.z * dx;
                float h0 = sx * dx;
                float h1 = fmaf(1024.0f, p.z, fmaf(64.0f, sx, h0));  // col +32
                eb0[u] = FAST_EXP2(h0);
                eb1[u] = FAST_EXP2(h1);
            }
            A0.h[jp] = PKRTZ(ea0[0], ea0[1]);
            A1.h[jp] = PKRTZ(ea1[0], ea1[1]);
            B0.h[jp] = PKRTZ(eb0[0], eb0[1]);
            B1.h[jp] = PKRTZ(eb1[0], eb1[1]);
        }
        acc[0][0] = __builtin_amdgcn_mfma_f32_32x32x16_f16(A0.v, B0.v, acc[0][0], 0, 0, 0);
        acc[0][1] = __builtin_amdgcn_mfma_f32_32x32x16_f16(A0.v, B1.v, acc[0][1], 0, 0, 0);
        acc[1][0] = __builtin_amdgcn_mfma_f32_32x32x16_f16(A1.v, B0.v, acc[1][0], 0, 0, 0);
        acc[1][1] = __builtin_amdgcn_mfma_f32_32x32x16_f16(A1.v, B1.v, acc[1][1], 0, 0, 0);
    }

    // cross-half reduce: [j][lane] layout (lane-consecutive -> conflict-free)
    float* rq = red + quad * 4096;
    if (half == 0) {
#pragma unroll
        for (int rr = 0; rr < 2; ++rr)
#pragma unroll
            for (int cb = 0; cb < 2; ++cb) {
                float* t = rq + (rr * 2 + cb) * 1024 + lane;
#pragma unroll
                for (int j = 0; j < 16; ++j) t[j * 64] = acc[rr][cb][j];
            }
    }
    __syncthreads();

    if (half == 1) {
        f16* base = part + ((size_t)(b * NS + ks)) * (S * S) + lane * 16;
#pragma unroll
        for (int rr = 0; rr < 2; ++rr)
#pragma unroll
            for (int cb = 0; cb < 2; ++cb) {
                float* t = rq + (rr * 2 + cb) * 1024 + lane;
                floatx16 v = acc[rr][cb];
#pragma unroll
                for (int j = 0; j < 16; ++j) v[j] += t[j * 64];
                // image 32x32 tile: r = (quad>>1)*2+rr, c = (quad&1)*2+cb
                const int tileidx = ((quad >> 1) * 2 + rr) * 4 + ((quad & 1) * 2 + cb);
                f16* pq = base + (size_t)tileidx * 1024;
                frag_u lo, hiv;
#pragma unroll
                for (int jp = 0; jp < 4; ++jp) {
                    lo.h[jp]  = PKRTZ(v[2 * jp],     v[2 * jp + 1]);
                    hiv.h[jp] = PKRTZ(v[2 * jp + 8], v[2 * jp + 9]);
                }
                *(f16x8*)(pq + 0) = lo.v;
                *(f16x8*)(pq + 8) = hiv.v;
            }
    }
}

// sum NS f16 partials per batch (f16x8 coalesced reads), un-permute, write f32.
__global__ __launch_bounds__(256) void k_reduce(const f16* __restrict__ part,
                                                float* __restrict__ out) {
    const int b  = blockIdx.z;
    const int f8 = (blockIdx.x * 256 + threadIdx.x) * 8;   // frag-order base idx

    const f16* src = part + (size_t)b * NS * (S * S) + f8;
    float s0[8] = {0.f}, s1[8] = {0.f};
    for (int s = 0; s < NS; s += 2) {                      // NS even
        f16x8 v0 = *(const f16x8*)&src[(size_t)s * (S * S)];
        f16x8 v1 = *(const f16x8*)&src[(size_t)(s + 1) * (S * S)];
#pragma unroll
        for (int i = 0; i < 8; ++i) { s0[i] += (float)v0[i]; s1[i] += (float)v1[i]; }
    }

    // decode f8 = tile*1024 + lane*16 + reg0; tile = r*4 + c (32x32 tiles)
    const int reg0 = f8 & 15;
    const int lane = (f8 >> 4) & 63;
    const int tile = f8 >> 10;
    const int r    = tile >> 2;
    const int cc   = tile & 3;
    // mfma_32x32 C/D: col = lane&31, row = (reg&3) + 8*(reg>>2) + 4*(lane>>5)
    const int rowb = r * 32 + 4 * (lane >> 5);
    const int col  = cc * 32 + (lane & 31);
#pragma unroll
    for (int i = 0; i < 8; ++i) {
        const int reg = reg0 + i;
        const int row = rowb + (reg & 3) + 8 * (reg >> 2);
        out[((size_t)b * S + row) * S + col] = s0[i] + s1[i];
    }
}

extern "C" void kernel_launch(void* const* d_in, const int* in_sizes, int n_in,
                              void* d_out, int out_size, void* d_ws, size_t ws_size,
                              hipStream_t stream) {
    const float* mol  = (const float*)d_in[0];
    const float* stds = (const float*)d_in[1];
    const float* dens = (const float*)d_in[2];
    float* out = (float*)d_out;

    const int A = in_sizes[1];             // 20000
    const int B = in_sizes[0] / (A * 3);   // 16

    f16* part = (f16*)d_ws;                // B*NS*16384*2 = 16.8 MB

    k_proj<<<dim3(NS, B), dim3(BLOCK), 0, stream>>>(mol, stds, dens, part, B, A);
    k_reduce<<<dim3((S * S) / (256 * 8), 1, B), dim3(256), 0, stream>>>(part, out);
}